// Round 1
// 625.957 us; speedup vs baseline: 1.1505x; 1.1505x over previous
//
#include <hip/hip_runtime.h>

#define H 512
#define W 512
#define NIMG 128
#define TH 16
#define TW 128
#define XR (TH + 6)        // 22 staged rows
#define XSTRIDE 136        // xin row stride (floats); covers gx = x0-4 .. x0+131

#define YHR_OFF ((long)NIMG * H * W)                      // 33554432
#define BSTRIDE ((long)(H / 2) * (W / 2))                 // 65536
#define YH_SIZE ((long)NIMG * 6 * BSTRIDE)                // 50331648
#define YHI_OFF (YHR_OFF + YH_SIZE)                       // 83886080

__device__ __forceinline__ int reflect512(int g) {
    // symmetric (edge-inclusive) reflection, single fold is enough for |halo|<=4
    g = (g < 0) ? (-1 - g) : g;
    g = (g > H - 1) ? (2 * H - 1 - g) : g;
    return g;
}

__device__ __forceinline__ float4 f4fma(float s, float4 a, float4 acc) {
    acc.x = fmaf(s, a.x, acc.x);
    acc.y = fmaf(s, a.y, acc.y);
    acc.z = fmaf(s, a.z, acc.z);
    acc.w = fmaf(s, a.w, acc.w);
    return acc;
}

__global__ __launch_bounds__(256, 4)
void dtcwt_fwd1(const float* __restrict__ x,
                const float* __restrict__ h0o,
                const float* __restrict__ h1o,
                float* __restrict__ out)
{
    // local col c of xin <-> gx = x0 - 4 + c  (4-wide halo each side keeps float4 alignment;
    // filter only needs 3, cols 0 and 135 are staged-but-unused)
    __shared__ __align__(16) float xin[XR][XSTRIDE];
    __shared__ __align__(16) float slo[XR][TW];
    __shared__ __align__(16) float shi[XR][TW];

    const int tid = threadIdx.x;
    const int x0 = blockIdx.x * TW;
    const int y0 = blockIdx.y * TH;
    const int img = blockIdx.z;

    // taps: uniform address -> s_load into SGPRs
    float c0[5], c1[7];
#pragma unroll
    for (int j = 0; j < 5; ++j) c0[j] = h0o[j];
#pragma unroll
    for (int j = 0; j < 7; ++j) c1[j] = h1o[j];

    const long ibase = (long)img * (H * W);

    // ---- Phase 1a: bulk, float4 — gx = x0 + 4*c4 is always in [0, 511], no x-reflect ----
    for (int i = tid; i < XR * (TW / 4); i += 256) {
        int r = i >> 5;                // 0..21
        int c4 = i & 31;               // 0..31
        int gy = reflect512(y0 - 3 + r);
        float4 v = *(const float4*)&x[ibase + (long)gy * W + x0 + c4 * 4];
        *(float4*)&xin[r][4 + c4 * 4] = v;
    }
    // ---- Phase 1b: halo ring, 8 cols x 22 rows, scalar with reflect ----
    if (tid < XR * 8) {
        int r = tid >> 3;
        int c = tid & 7;
        int lc = (c < 4) ? c : (124 + c);          // 0..3 or 128..131... -> cols 0..3,128+c-4? see below
        lc = (c < 4) ? c : (128 + (c - 4) + 4);    // cols 132..135
        int gy = reflect512(y0 - 3 + r);
        int gx = reflect512(x0 - 4 + lc);
        xin[r][lc] = x[ibase + (long)gy * W + gx];
    }
    __syncthreads();

    // ---- Phase 2: row filters, float4 in / float4 out ----
    // output w = w0+k (abs x0+w): Lo = sum_j c0[j]*xin[r][w+2+j], Hi = sum_j c1[j]*xin[r][w+1+j]
    for (int i = tid; i < XR * (TW / 4); i += 256) {
        int r = i >> 5;
        int w0 = (i & 31) * 4;
        float4 A  = *(const float4*)&xin[r][w0];
        float4 Bv = *(const float4*)&xin[r][w0 + 4];
        float4 Cv = *(const float4*)&xin[r][w0 + 8];
        float f1 = A.y, f2 = A.z, f3 = A.w;
        float f4 = Bv.x, f5 = Bv.y, f6 = Bv.z, f7 = Bv.w;
        float f8 = Cv.x, f9 = Cv.y, f10 = Cv.z;
        float lo0 = c0[0]*f2 + c0[1]*f3 + c0[2]*f4 + c0[3]*f5 + c0[4]*f6;
        float lo1 = c0[0]*f3 + c0[1]*f4 + c0[2]*f5 + c0[3]*f6 + c0[4]*f7;
        float lo2 = c0[0]*f4 + c0[1]*f5 + c0[2]*f6 + c0[3]*f7 + c0[4]*f8;
        float lo3 = c0[0]*f5 + c0[1]*f6 + c0[2]*f7 + c0[3]*f8 + c0[4]*f9;
        float hi0 = c1[0]*f1 + c1[1]*f2 + c1[2]*f3 + c1[3]*f4 + c1[4]*f5 + c1[5]*f6 + c1[6]*f7;
        float hi1 = c1[0]*f2 + c1[1]*f3 + c1[2]*f4 + c1[3]*f5 + c1[4]*f6 + c1[5]*f7 + c1[6]*f8;
        float hi2 = c1[0]*f3 + c1[1]*f4 + c1[2]*f5 + c1[3]*f6 + c1[4]*f7 + c1[5]*f8 + c1[6]*f9;
        float hi3 = c1[0]*f4 + c1[1]*f5 + c1[2]*f6 + c1[3]*f7 + c1[4]*f8 + c1[5]*f9 + c1[6]*f10;
        *(float4*)&slo[r][w0] = make_float4(lo0, lo1, lo2, lo3);
        *(float4*)&shi[r][w0] = make_float4(hi0, hi1, hi2, hi3);
    }
    __syncthreads();

    // ---- Phase 3: column filters + q2c, one thread = 2x4 pixel block (2 quads), 1 pass ----
    {
        const int qr = tid >> 5;       // 0..7
        const int q4 = tid & 31;       // 0..31
        const int r0 = qr * 2;         // top local row
        const int w0 = q4 * 4;         // left local col

        float4 L[8];
#pragma unroll
        for (int j = 0; j < 8; ++j) L[j] = *(const float4*)&slo[r0 + j][w0];

        float4 ll0 = make_float4(0.f, 0.f, 0.f, 0.f);
        float4 ll1 = ll0, lh0 = ll0, lh1 = ll0;
#pragma unroll
        for (int j = 0; j < 5; ++j) {
            ll0 = f4fma(c0[j], L[1 + j], ll0);
            ll1 = f4fma(c0[j], L[2 + j], ll1);
        }
#pragma unroll
        for (int j = 0; j < 7; ++j) {
            lh0 = f4fma(c1[j], L[j],     lh0);
            lh1 = f4fma(c1[j], L[1 + j], lh1);
        }

        // Yl = LoLo, full resolution, float4 rows
        const long ylb = ibase + (long)(y0 + r0) * W + (x0 + w0);
        *(float4*)&out[ylb]     = ll0;
        *(float4*)&out[ylb + W] = ll1;

        float4 Hv[8];
#pragma unroll
        for (int j = 0; j < 8; ++j) Hv[j] = *(const float4*)&shi[r0 + j][w0];

        float4 hl0 = make_float4(0.f, 0.f, 0.f, 0.f);
        float4 hl1 = hl0, hh0 = hl0, hh1 = hl0;
#pragma unroll
        for (int j = 0; j < 5; ++j) {
            hl0 = f4fma(c0[j], Hv[1 + j], hl0);
            hl1 = f4fma(c0[j], Hv[2 + j], hl1);
        }
#pragma unroll
        for (int j = 0; j < 7; ++j) {
            hh0 = f4fma(c1[j], Hv[j],     hh0);
            hh1 = f4fma(c1[j], Hv[1 + j], hh1);
        }

        // q2c on two horizontally-adjacent quads: quadA = cols (.x,.y), quadB = cols (.z,.w)
        // a=row0.even b=row0.odd c=row1.even d=row1.odd; z1=(a-d, b+c), z2=(a+d, b-c)
        // bands: 0=LoHi.z1 1=HiHi.z1 2=HiLo.z1 3=HiLo.z2 4=HiHi.z2 5=LoHi.z2
        const float s = 0.70710678118654752440f;
        const int qy = (y0 >> 1) + qr;
        const int qx = (x0 >> 1) + q4 * 2;
        const long hb = (long)img * 6 * BSTRIDE + (long)qy * (W / 2) + qx;
        float* __restrict__ yhr = out + YHR_OFF;
        float* __restrict__ yhi = out + YHI_OFF;

        *(float2*)&yhr[hb + 0 * BSTRIDE] = make_float2((lh0.x - lh1.y) * s, (lh0.z - lh1.w) * s);
        *(float2*)&yhi[hb + 0 * BSTRIDE] = make_float2((lh0.y + lh1.x) * s, (lh0.w + lh1.z) * s);
        *(float2*)&yhr[hb + 1 * BSTRIDE] = make_float2((hh0.x - hh1.y) * s, (hh0.z - hh1.w) * s);
        *(float2*)&yhi[hb + 1 * BSTRIDE] = make_float2((hh0.y + hh1.x) * s, (hh0.w + hh1.z) * s);
        *(float2*)&yhr[hb + 2 * BSTRIDE] = make_float2((hl0.x - hl1.y) * s, (hl0.z - hl1.w) * s);
        *(float2*)&yhi[hb + 2 * BSTRIDE] = make_float2((hl0.y + hl1.x) * s, (hl0.w + hl1.z) * s);
        *(float2*)&yhr[hb + 3 * BSTRIDE] = make_float2((hl0.x + hl1.y) * s, (hl0.z + hl1.w) * s);
        *(float2*)&yhi[hb + 3 * BSTRIDE] = make_float2((hl0.y - hl1.x) * s, (hl0.w - hl1.z) * s);
        *(float2*)&yhr[hb + 4 * BSTRIDE] = make_float2((hh0.x + hh1.y) * s, (hh0.z + hh1.w) * s);
        *(float2*)&yhi[hb + 4 * BSTRIDE] = make_float2((hh0.y - hh1.x) * s, (hh0.w - hh1.z) * s);
        *(float2*)&yhr[hb + 5 * BSTRIDE] = make_float2((lh0.x + lh1.y) * s, (lh0.z + lh1.w) * s);
        *(float2*)&yhi[hb + 5 * BSTRIDE] = make_float2((lh0.y - lh1.x) * s, (lh0.w - lh1.z) * s);
    }
}

extern "C" void kernel_launch(void* const* d_in, const int* in_sizes, int n_in,
                              void* d_out, int out_size, void* d_ws, size_t ws_size,
                              hipStream_t stream) {
    const float* x   = (const float*)d_in[0];
    const float* h0o = (const float*)d_in[1];
    const float* h1o = (const float*)d_in[2];
    float* out = (float*)d_out;
    dim3 grid(W / TW, H / TH, NIMG);   // 4 x 32 x 128
    dtcwt_fwd1<<<grid, dim3(256), 0, stream>>>(x, h0o, h1o, out);
}